// Round 2
// baseline (558.793 us; speedup 1.0000x reference)
//
#include <hip/hip_runtime.h>

#define N_NODES   50000
#define N_EDGES   800000
#define IN_DIM    89
#define HID       128
#define N_CLASSES 64
#define N_GRAPHS  64

// ---------------------------------------------------------------------------
// row_ptr via binary search: dst is sorted, graph_id is sorted.
// ---------------------------------------------------------------------------
__global__ void rowptr_kernel(const int* __restrict__ dst,
                              const int* __restrict__ gid,
                              int* __restrict__ node_ptr,
                              int* __restrict__ graph_ptr) {
    int i = blockIdx.x * blockDim.x + threadIdx.x;
    if (i <= N_NODES) {
        int lo = 0, hi = N_EDGES;
        while (lo < hi) { int mid = (lo + hi) >> 1; if (dst[mid] < i) lo = mid + 1; else hi = mid; }
        node_ptr[i] = lo;
    }
    if (i <= N_GRAPHS) {
        int lo = 0, hi = N_NODES;
        while (lo < hi) { int mid = (lo + hi) >> 1; if (gid[mid] < i) lo = mid + 1; else hi = mid; }
        graph_ptr[i] = lo;
    }
}

// ---------------------------------------------------------------------------
// 128-dim mean aggregation + bias + ReLU, wave-per-node.
// Lanes 0-31 handle even edges, lanes 32-63 odd edges; each lane reads one
// float4 (dims 4*(lane&31) .. +3). One 16B-vector wave instruction covers
// 2 edges. Halves combined with shfl_xor(32).
// out[v] = relu( (1/max(deg,1)) * sum_e P[src[e]] + bias )
// ---------------------------------------------------------------------------
__global__ void agg128_kernel(const float* __restrict__ P,
                              const int* __restrict__ src,
                              const int* __restrict__ node_ptr,
                              const float* __restrict__ bias,
                              float* __restrict__ out) {
    const int wave = threadIdx.x >> 6;          // 0..3
    const int lane = threadIdx.x & 63;
    const int v    = blockIdx.x * 4 + wave;
    if (v >= N_NODES) return;

    const int lo = node_ptr[v];
    const int hi = node_ptr[v + 1];
    const float inv = 1.0f / (float)max(hi - lo, 1);

    const int half = lane >> 5;                 // 0 or 1
    const int c4   = lane & 31;                 // float4 slot: dims [4*c4, 4*c4+4)

    float4 acc = make_float4(0.f, 0.f, 0.f, 0.f);
    for (int e = lo + half; e < hi; e += 2) {
        const int u = src[e];
        const float4 r = *reinterpret_cast<const float4*>(P + (size_t)u * HID + c4 * 4);
        acc.x += r.x; acc.y += r.y; acc.z += r.z; acc.w += r.w;
    }
    // combine the two halves (same dims, disjoint edges)
    acc.x += __shfl_xor(acc.x, 32);
    acc.y += __shfl_xor(acc.y, 32);
    acc.z += __shfl_xor(acc.z, 32);
    acc.w += __shfl_xor(acc.w, 32);

    if (half == 0) {
        const float4 b4 = *reinterpret_cast<const float4*>(bias + c4 * 4);
        float4 o;
        o.x = fmaxf(acc.x * inv + b4.x, 0.f);
        o.y = fmaxf(acc.y * inv + b4.y, 0.f);
        o.z = fmaxf(acc.z * inv + b4.z, 0.f);
        o.w = fmaxf(acc.w * inv + b4.w, 0.f);
        *reinterpret_cast<float4*>(out + (size_t)v * HID + c4 * 4) = o;
    }
}

// ---------------------------------------------------------------------------
// Y[M x N] = X[M x K] @ W[K x N]   (plain, no bias/relu — epilogue lives in agg)
// 32 rows per block (128 threads = one output column each).
// ---------------------------------------------------------------------------
template <int K, int N>
__global__ void linear_kernel(const float* __restrict__ X,
                              const float* __restrict__ W,
                              float* __restrict__ Y, int M) {
    constexpr int R = 32;
    __shared__ float xs[R][K + 1];
    const int row0 = blockIdx.x * R;
    const int j    = threadIdx.x;               // N threads

    for (int idx = threadIdx.x; idx < R * K; idx += N) {
        const int r = idx / K, k = idx - r * K;
        const int row = row0 + r;
        xs[r][k] = (row < M) ? X[(size_t)row * K + k] : 0.0f;
    }
    __syncthreads();

    float acc[R];
#pragma unroll
    for (int r = 0; r < R; ++r) acc[r] = 0.0f;

#pragma unroll 4
    for (int k = 0; k < K; ++k) {
        const float wv = W[k * N + j];
#pragma unroll
        for (int r = 0; r < R; ++r) acc[r] = fmaf(xs[r][k], wv, acc[r]);
    }

#pragma unroll
    for (int r = 0; r < R; ++r) {
        const int row = row0 + r;
        if (row < M) Y[(size_t)row * N + j] = acc[r];
    }
}

// ---------------------------------------------------------------------------
// Per-graph mean pooling (graph_id sorted). 8 partial blocks per graph.
// ---------------------------------------------------------------------------
__global__ void pool_kernel(const float* __restrict__ h,
                            const int* __restrict__ graph_ptr,
                            float* __restrict__ hg) {
    constexpr int SPLIT = 8;
    const int g   = blockIdx.x / SPLIT;
    const int s   = blockIdx.x % SPLIT;
    const int tid = threadIdx.x;                // 128
    const int lo  = graph_ptr[g];
    const int hi  = graph_ptr[g + 1];
    const float inv = 1.0f / (float)max(hi - lo, 1);

    float acc = 0.0f;
    for (int r = lo + s; r < hi; r += SPLIT)
        acc += h[(size_t)r * HID + tid];
    if (acc != 0.0f || s == 0)
        atomicAdd(&hg[g * HID + tid], acc * inv);
}

// ---------------------------------------------------------------------------
// Classifier head.
// ---------------------------------------------------------------------------
__global__ void cls1_kernel(const float* __restrict__ hg,
                            const float* __restrict__ Wc1,
                            const float* __restrict__ bc1,
                            float* __restrict__ t) {
    const int g = blockIdx.x;                   // 64
    const int j = threadIdx.x;                  // 128
    __shared__ float row[HID];
    row[j] = hg[g * HID + j];
    __syncthreads();
    float acc = bc1[j];
    for (int k = 0; k < HID; ++k) acc += row[k] * Wc1[k * HID + j];
    t[g * HID + j] = fmaxf(acc, 0.0f);
}

__global__ void cls2_kernel(const float* __restrict__ t,
                            const float* __restrict__ Wc2,
                            const float* __restrict__ bc2,
                            float* __restrict__ out) {
    const int g = blockIdx.x;                   // 64
    const int j = threadIdx.x;                  // 64
    __shared__ float row[HID];
    row[j]      = t[g * HID + j];
    row[j + 64] = t[g * HID + j + 64];
    __syncthreads();
    float acc = bc2[j];
    for (int k = 0; k < HID; ++k) acc += row[k] * Wc2[k * N_CLASSES + j];
    out[g * N_CLASSES + j] = acc;
}

// ---------------------------------------------------------------------------
extern "C" void kernel_launch(void* const* d_in, const int* in_sizes, int n_in,
                              void* d_out, int out_size, void* d_ws, size_t ws_size,
                              hipStream_t stream) {
    const float* nf   = (const float*)d_in[0];
    const int*   src  = (const int*)  d_in[1];
    const int*   dst  = (const int*)  d_in[2];
    const int*   gid  = (const int*)  d_in[3];
    const float* W1  = (const float*)d_in[5];
    const float* b1  = (const float*)d_in[6];
    const float* W2  = (const float*)d_in[7];
    const float* b2  = (const float*)d_in[8];
    const float* W3  = (const float*)d_in[9];
    const float* b3  = (const float*)d_in[10];
    const float* Wc1 = (const float*)d_in[11];
    const float* bc1 = (const float*)d_in[12];
    const float* Wc2 = (const float*)d_in[13];
    const float* bc2 = (const float*)d_in[14];
    float* out = (float*)d_out;

    char* ws = (char*)d_ws;
    size_t off = 0;
    auto alloc = [&](size_t bytes) { void* p = ws + off; off = (off + bytes + 255) & ~(size_t)255; return p; };
    int*   node_ptr  = (int*)  alloc((N_NODES + 1) * sizeof(int));
    int*   graph_ptr = (int*)  alloc((N_GRAPHS + 1) * sizeof(int));
    float* bufP      = (float*)alloc((size_t)N_NODES * HID * sizeof(float)); // projected features
    float* bufH      = (float*)alloc((size_t)N_NODES * HID * sizeof(float)); // hidden state
    float* hg        = (float*)alloc(N_GRAPHS * HID * sizeof(float));
    float* tbuf      = (float*)alloc(N_GRAPHS * HID * sizeof(float));
    (void)ws_size;

    const int AGG_GRID = (N_NODES + 3) / 4;     // 4 waves/block, wave-per-node
    const int LIN_GRID = (N_NODES + 31) / 32;

    // CSR pointers
    rowptr_kernel<<<(N_NODES + 256) / 256, 256, 0, stream>>>(dst, gid, node_ptr, graph_ptr);

    // Layer 1: P = nf @ W1 ; h = relu(agg(P) + b1)
    linear_kernel<IN_DIM, HID><<<LIN_GRID, HID, 0, stream>>>(nf, W1, bufP, N_NODES);
    agg128_kernel<<<AGG_GRID, 256, 0, stream>>>(bufP, src, node_ptr, b1, bufH);

    // Layer 2
    linear_kernel<HID, HID><<<LIN_GRID, HID, 0, stream>>>(bufH, W2, bufP, N_NODES);
    agg128_kernel<<<AGG_GRID, 256, 0, stream>>>(bufP, src, node_ptr, b2, bufH);

    // Layer 3
    linear_kernel<HID, HID><<<LIN_GRID, HID, 0, stream>>>(bufH, W3, bufP, N_NODES);
    agg128_kernel<<<AGG_GRID, 256, 0, stream>>>(bufP, src, node_ptr, b3, bufH);

    // Graph mean pool
    hipMemsetAsync(hg, 0, N_GRAPHS * HID * sizeof(float), stream);
    pool_kernel<<<N_GRAPHS * 8, HID, 0, stream>>>(bufH, graph_ptr, hg);

    // Classifier head
    cls1_kernel<<<N_GRAPHS, HID, 0, stream>>>(hg, Wc1, bc1, tbuf);
    cls2_kernel<<<N_GRAPHS, N_CLASSES, 0, stream>>>(tbuf, Wc2, bc2, out);
}

// Round 3
// 348.286 us; speedup vs baseline: 1.6044x; 1.6044x over previous
//
#include <hip/hip_runtime.h>

#define N_NODES   50000
#define N_EDGES   800000
#define IN_DIM    89
#define HID       128
#define N_CLASSES 64
#define N_GRAPHS  64

// ---------------------------------------------------------------------------
// row_ptr via binary search: dst is sorted, graph_id is sorted.
// ---------------------------------------------------------------------------
__global__ void rowptr_kernel(const int* __restrict__ dst,
                              const int* __restrict__ gid,
                              int* __restrict__ node_ptr,
                              int* __restrict__ graph_ptr) {
    int i = blockIdx.x * blockDim.x + threadIdx.x;
    if (i <= N_NODES) {
        int lo = 0, hi = N_EDGES;
        while (lo < hi) { int mid = (lo + hi) >> 1; if (dst[mid] < i) lo = mid + 1; else hi = mid; }
        node_ptr[i] = lo;
    }
    if (i <= N_GRAPHS) {
        int lo = 0, hi = N_NODES;
        while (lo < hi) { int mid = (lo + hi) >> 1; if (gid[mid] < i) lo = mid + 1; else hi = mid; }
        graph_ptr[i] = lo;
    }
}

// ---------------------------------------------------------------------------
// 128-dim mean aggregation + bias + ReLU, wave-per-node (dst-sorted CSR).
// ---------------------------------------------------------------------------
__global__ void agg128_kernel(const float* __restrict__ P,
                              const int* __restrict__ src,
                              const int* __restrict__ node_ptr,
                              const float* __restrict__ bias,
                              float* __restrict__ out) {
    const int wave = threadIdx.x >> 6;          // 0..3
    const int lane = threadIdx.x & 63;
    const int v    = blockIdx.x * 4 + wave;
    if (v >= N_NODES) return;

    const int lo = node_ptr[v];
    const int hi = node_ptr[v + 1];
    const float inv = 1.0f / (float)max(hi - lo, 1);

    const int half = lane >> 5;                 // 0 or 1
    const int c4   = lane & 31;                 // float4 slot

    float4 acc = make_float4(0.f, 0.f, 0.f, 0.f);
    for (int e = lo + half; e < hi; e += 2) {
        const int u = src[e];
        const float4 r = *reinterpret_cast<const float4*>(P + (size_t)u * HID + c4 * 4);
        acc.x += r.x; acc.y += r.y; acc.z += r.z; acc.w += r.w;
    }
    acc.x += __shfl_xor(acc.x, 32);
    acc.y += __shfl_xor(acc.y, 32);
    acc.z += __shfl_xor(acc.z, 32);
    acc.w += __shfl_xor(acc.w, 32);

    if (half == 0) {
        const float4 b4 = *reinterpret_cast<const float4*>(bias + c4 * 4);
        float4 o;
        o.x = fmaxf(acc.x * inv + b4.x, 0.f);
        o.y = fmaxf(acc.y * inv + b4.y, 0.f);
        o.z = fmaxf(acc.z * inv + b4.z, 0.f);
        o.w = fmaxf(acc.w * inv + b4.w, 0.f);
        *reinterpret_cast<float4*>(out + (size_t)v * HID + c4 * 4) = o;
    }
}

// ---------------------------------------------------------------------------
// Register-tiled fp32 GEMM: Y[M x 128] = X[M x K] @ W[K x 128].
// Block tile 64x128, 256 threads, thread tile 4 rows x 8 cols.
// Thread cols split [4tx,4tx+4) U [64+4tx, 64+4tx+4) -> W LDS reads are
// exactly 2-way per bank (free). X LDS reads are 16-way broadcast.
// ALIGN4: K%4==0 -> float4 X staging; else scalar staging (layer 1, K=89).
// ---------------------------------------------------------------------------
template <int K, bool ALIGN4>
__global__ __launch_bounds__(256) void gemm_kernel(const float* __restrict__ X,
                                                   const float* __restrict__ W,
                                                   float* __restrict__ Y, int M) {
    constexpr int BM = 64, BN = 128, KC = 64;
    __shared__ float xs[BM][KC + 4];   // [row][k], stride 68 (16B-aligned)
    __shared__ float ws[KC][BN];       // [k][col]

    const int tid  = threadIdx.x;
    const int tx   = tid & 15;         // col group
    const int ty   = tid >> 4;         // row group (0..15)
    const int row0 = blockIdx.x * BM;

    float acc[4][8];
#pragma unroll
    for (int r = 0; r < 4; ++r)
#pragma unroll
        for (int c = 0; c < 8; ++c) acc[r][c] = 0.f;

    for (int k0 = 0; k0 < K; k0 += KC) {
        const int kc = (K - k0 < KC) ? (K - k0) : KC;

        // ---- stage X tile ----
        if (ALIGN4) {
            // 64 rows x 64 k = 1024 float4, 4 per thread; coalesced reads.
#pragma unroll
            for (int it = 0; it < 4; ++it) {
                const int flat = tid + it * 256;     // 0..1023
                const int r    = flat >> 4;
                const int c4   = flat & 15;
                const int row  = row0 + r;
                float4 v = make_float4(0.f, 0.f, 0.f, 0.f);
                if (row < M)
                    v = *reinterpret_cast<const float4*>(X + (size_t)row * K + k0 + c4 * 4);
                *reinterpret_cast<float4*>(&xs[r][c4 * 4]) = v;
            }
        } else {
            // scalar staging (odd K), zero-fill beyond kc
            for (int i = tid; i < BM * KC; i += 256) {
                const int r   = i >> 6;
                const int k   = i & 63;
                const int row = row0 + r;
                xs[r][k] = (row < M && k < kc) ? X[(size_t)row * K + k0 + k] : 0.f;
            }
        }

        // ---- stage W tile: 64 x 128 = 2048 float4, 8 per thread ----
#pragma unroll
        for (int it = 0; it < 8; ++it) {
            const int flat = tid + it * 256;         // 0..2047
            const int k    = flat >> 5;
            const int c4   = flat & 31;
            float4 v = make_float4(0.f, 0.f, 0.f, 0.f);
            if (k < kc)
                v = *reinterpret_cast<const float4*>(W + (size_t)(k0 + k) * BN + c4 * 4);
            *reinterpret_cast<float4*>(&ws[k][c4 * 4]) = v;
        }
        __syncthreads();

        // ---- compute: unroll k by 4, b128 LDS reads ----
        const int kend = (kc + 3) & ~3;              // zero-padded staging makes this safe
        for (int k = 0; k < kend; k += 4) {
            float xv[4][4];
#pragma unroll
            for (int r = 0; r < 4; ++r) {
                const float4 t = *reinterpret_cast<const float4*>(&xs[ty * 4 + r][k]);
                xv[r][0] = t.x; xv[r][1] = t.y; xv[r][2] = t.z; xv[r][3] = t.w;
            }
#pragma unroll
            for (int kk = 0; kk < 4; ++kk) {
                const float4 wa = *reinterpret_cast<const float4*>(&ws[k + kk][tx * 4]);
                const float4 wb = *reinterpret_cast<const float4*>(&ws[k + kk][64 + tx * 4]);
                const float wc[8] = {wa.x, wa.y, wa.z, wa.w, wb.x, wb.y, wb.z, wb.w};
#pragma unroll
                for (int r = 0; r < 4; ++r)
#pragma unroll
                    for (int c = 0; c < 8; ++c)
                        acc[r][c] = fmaf(xv[r][kk], wc[c], acc[r][c]);
            }
        }
        __syncthreads();
    }

    // ---- store ----
#pragma unroll
    for (int r = 0; r < 4; ++r) {
        const int row = row0 + ty * 4 + r;
        if (row < M) {
            float4 a = make_float4(acc[r][0], acc[r][1], acc[r][2], acc[r][3]);
            float4 b = make_float4(acc[r][4], acc[r][5], acc[r][6], acc[r][7]);
            *reinterpret_cast<float4*>(Y + (size_t)row * BN + tx * 4)      = a;
            *reinterpret_cast<float4*>(Y + (size_t)row * BN + 64 + tx * 4) = b;
        }
    }
}

// ---------------------------------------------------------------------------
// Per-graph mean pooling (graph_id sorted). 8 partial blocks per graph.
// ---------------------------------------------------------------------------
__global__ void pool_kernel(const float* __restrict__ h,
                            const int* __restrict__ graph_ptr,
                            float* __restrict__ hg) {
    constexpr int SPLIT = 8;
    const int g   = blockIdx.x / SPLIT;
    const int s   = blockIdx.x % SPLIT;
    const int tid = threadIdx.x;                // 128
    const int lo  = graph_ptr[g];
    const int hi  = graph_ptr[g + 1];
    const float inv = 1.0f / (float)max(hi - lo, 1);

    float acc = 0.0f;
    for (int r = lo + s; r < hi; r += SPLIT)
        acc += h[(size_t)r * HID + tid];
    if (acc != 0.0f || s == 0)
        atomicAdd(&hg[g * HID + tid], acc * inv);
}

// ---------------------------------------------------------------------------
// Classifier head.
// ---------------------------------------------------------------------------
__global__ void cls1_kernel(const float* __restrict__ hg,
                            const float* __restrict__ Wc1,
                            const float* __restrict__ bc1,
                            float* __restrict__ t) {
    const int g = blockIdx.x;                   // 64
    const int j = threadIdx.x;                  // 128
    __shared__ float row[HID];
    row[j] = hg[g * HID + j];
    __syncthreads();
    float acc = bc1[j];
    for (int k = 0; k < HID; ++k) acc += row[k] * Wc1[k * HID + j];
    t[g * HID + j] = fmaxf(acc, 0.0f);
}

__global__ void cls2_kernel(const float* __restrict__ t,
                            const float* __restrict__ Wc2,
                            const float* __restrict__ bc2,
                            float* __restrict__ out) {
    const int g = blockIdx.x;                   // 64
    const int j = threadIdx.x;                  // 64
    __shared__ float row[HID];
    row[j]      = t[g * HID + j];
    row[j + 64] = t[g * HID + j + 64];
    __syncthreads();
    float acc = bc2[j];
    for (int k = 0; k < HID; ++k) acc += row[k] * Wc2[k * N_CLASSES + j];
    out[g * N_CLASSES + j] = acc;
}

// ---------------------------------------------------------------------------
extern "C" void kernel_launch(void* const* d_in, const int* in_sizes, int n_in,
                              void* d_out, int out_size, void* d_ws, size_t ws_size,
                              hipStream_t stream) {
    const float* nf   = (const float*)d_in[0];
    const int*   src  = (const int*)  d_in[1];
    const int*   dst  = (const int*)  d_in[2];
    const int*   gid  = (const int*)  d_in[3];
    const float* W1  = (const float*)d_in[5];
    const float* b1  = (const float*)d_in[6];
    const float* W2  = (const float*)d_in[7];
    const float* b2  = (const float*)d_in[8];
    const float* W3  = (const float*)d_in[9];
    const float* b3  = (const float*)d_in[10];
    const float* Wc1 = (const float*)d_in[11];
    const float* bc1 = (const float*)d_in[12];
    const float* Wc2 = (const float*)d_in[13];
    const float* bc2 = (const float*)d_in[14];
    float* out = (float*)d_out;

    char* ws = (char*)d_ws;
    size_t off = 0;
    auto alloc = [&](size_t bytes) { void* p = ws + off; off = (off + bytes + 255) & ~(size_t)255; return p; };
    int*   node_ptr  = (int*)  alloc((N_NODES + 1) * sizeof(int));
    int*   graph_ptr = (int*)  alloc((N_GRAPHS + 1) * sizeof(int));
    float* bufP      = (float*)alloc((size_t)N_NODES * HID * sizeof(float));
    float* bufH      = (float*)alloc((size_t)N_NODES * HID * sizeof(float));
    float* hg        = (float*)alloc(N_GRAPHS * HID * sizeof(float));
    float* tbuf      = (float*)alloc(N_GRAPHS * HID * sizeof(float));
    (void)ws_size;

    const int AGG_GRID  = (N_NODES + 3) / 4;
    const int GEMM_GRID = (N_NODES + 63) / 64;

    // CSR pointers
    rowptr_kernel<<<(N_NODES + 256) / 256, 256, 0, stream>>>(dst, gid, node_ptr, graph_ptr);

    // Layer 1: P = nf @ W1 ; h = relu(agg(P) + b1)
    gemm_kernel<IN_DIM, false><<<GEMM_GRID, 256, 0, stream>>>(nf, W1, bufP, N_NODES);
    agg128_kernel<<<AGG_GRID, 256, 0, stream>>>(bufP, src, node_ptr, b1, bufH);

    // Layer 2
    gemm_kernel<HID, true><<<GEMM_GRID, 256, 0, stream>>>(bufH, W2, bufP, N_NODES);
    agg128_kernel<<<AGG_GRID, 256, 0, stream>>>(bufP, src, node_ptr, b2, bufH);

    // Layer 3
    gemm_kernel<HID, true><<<GEMM_GRID, 256, 0, stream>>>(bufH, W3, bufP, N_NODES);
    agg128_kernel<<<AGG_GRID, 256, 0, stream>>>(bufP, src, node_ptr, b3, bufH);

    // Graph mean pool
    hipMemsetAsync(hg, 0, N_GRAPHS * HID * sizeof(float), stream);
    pool_kernel<<<N_GRAPHS * 8, HID, 0, stream>>>(bufH, graph_ptr, hg);

    // Classifier head
    cls1_kernel<<<N_GRAPHS, HID, 0, stream>>>(hg, Wc1, bc1, tbuf);
    cls2_kernel<<<N_GRAPHS, N_CLASSES, 0, stream>>>(tbuf, Wc2, bc2, out);
}

// Round 4
// 298.591 us; speedup vs baseline: 1.8714x; 1.1664x over previous
//
#include <hip/hip_runtime.h>

#define N_NODES   50000
#define N_EDGES   800000
#define IN_DIM    89
#define KP1       96      // IN_DIM padded to multiple of 32
#define HID       128
#define N_CLASSES 64
#define N_GRAPHS  64

typedef __attribute__((ext_vector_type(8))) short bf16x8;
typedef __attribute__((ext_vector_type(4))) float f32x4;

__device__ __forceinline__ unsigned short f2bf(float x) {
    union { float f; unsigned u; } v; v.f = x;
    unsigned r = v.u + 0x7FFF + ((v.u >> 16) & 1);   // RTNE
    return (unsigned short)(r >> 16);
}

// ---------------------------------------------------------------------------
// row_ptr via binary search: dst is sorted, graph_id is sorted.
// ---------------------------------------------------------------------------
__global__ void rowptr_kernel(const int* __restrict__ dst,
                              const int* __restrict__ gid,
                              int* __restrict__ node_ptr,
                              int* __restrict__ graph_ptr) {
    int i = blockIdx.x * blockDim.x + threadIdx.x;
    if (i <= N_NODES) {
        int lo = 0, hi = N_EDGES;
        while (lo < hi) { int mid = (lo + hi) >> 1; if (dst[mid] < i) lo = mid + 1; else hi = mid; }
        node_ptr[i] = lo;
    }
    if (i <= N_GRAPHS) {
        int lo = 0, hi = N_NODES;
        while (lo < hi) { int mid = (lo + hi) >> 1; if (gid[mid] < i) lo = mid + 1; else hi = mid; }
        graph_ptr[i] = lo;
    }
}

// ---------------------------------------------------------------------------
// nf (fp32, [M][89]) -> nfb (bf16, [M][96], zero-padded)
// ---------------------------------------------------------------------------
__global__ void conv_nf_kernel(const float* __restrict__ nf,
                               unsigned short* __restrict__ nfb) {
    const int i = blockIdx.x * 256 + threadIdx.x;
    if (i >= N_NODES * KP1) return;
    const int row = i / KP1, k = i - row * KP1;
    nfb[i] = (k < IN_DIM) ? f2bf(nf[(size_t)row * IN_DIM + k]) : (unsigned short)0;
}

// ---------------------------------------------------------------------------
// W (fp32, [K][128]) -> WT (bf16, [128][KPAD], transposed, zero-padded)
// ---------------------------------------------------------------------------
template <int K, int KPAD>
__global__ void prep_wt_kernel(const float* __restrict__ W,
                               unsigned short* __restrict__ WT) {
    const int i = blockIdx.x * 256 + threadIdx.x;
    if (i >= HID * KPAD) return;
    const int col = i / KPAD, k = i - col * KPAD;
    WT[i] = (k < K) ? f2bf(W[(size_t)k * HID + col]) : (unsigned short)0;
}

// ---------------------------------------------------------------------------
// MFMA GEMM: Y[M x 128] = Xb[M x KPAD](bf16) @ W (via WT[128 x KPAD] bf16).
// Block = 256 threads = 4 waves; wave handles 16 rows x 128 cols.
// No LDS: A fragments read once from global; B fragments from L1/L2-resident WT.
// A: lane reads Xb[row0+(l&15)][8*(l>>4)+k0 .. +8)
// B: lane reads WT[16*nf+(l&15)][8*(l>>4)+k0 .. +8)
// D: row=(l>>4)*4+reg, col=(l&15)   [m89/m91-verified layout]
// ---------------------------------------------------------------------------
template <int KPAD>
__global__ __launch_bounds__(256) void mfma_gemm_kernel(
        const unsigned short* __restrict__ Xb,
        const unsigned short* __restrict__ WT,
        float* __restrict__ Y, int M) {
    const int wave = threadIdx.x >> 6;
    const int lane = threadIdx.x & 63;
    const int r    = lane & 15;
    const int kg   = lane >> 4;                 // 0..3

    const int row  = blockIdx.x * 64 + wave * 16 + r;
    const int rowc = (row < M) ? row : (M - 1); // clamp loads; stores masked

    f32x4 acc[8];
#pragma unroll
    for (int i = 0; i < 8; ++i) acc[i] = (f32x4){0.f, 0.f, 0.f, 0.f};

    const unsigned short* xrow = Xb + (size_t)rowc * KPAD + kg * 8;

#pragma unroll
    for (int k0 = 0; k0 < KPAD; k0 += 32) {
        const bf16x8 a = *reinterpret_cast<const bf16x8*>(xrow + k0);
#pragma unroll
        for (int nf = 0; nf < 8; ++nf) {
            const bf16x8 b = *reinterpret_cast<const bf16x8*>(
                WT + (size_t)(nf * 16 + r) * KPAD + kg * 8 + k0);
            acc[nf] = __builtin_amdgcn_mfma_f32_16x16x32_bf16(a, b, acc[nf], 0, 0, 0);
        }
    }

    const int orow0 = blockIdx.x * 64 + wave * 16 + kg * 4;
#pragma unroll
    for (int nf = 0; nf < 8; ++nf) {
#pragma unroll
        for (int q = 0; q < 4; ++q) {
            const int orow = orow0 + q;
            if (orow < M) Y[(size_t)orow * HID + nf * 16 + r] = acc[nf][q];
        }
    }
}

// ---------------------------------------------------------------------------
// 128-dim mean aggregation + bias + ReLU, wave-per-node (dst-sorted CSR).
// OUT_BF16: write bf16 (feeds next MFMA GEMM); else fp32 (feeds pool).
// ---------------------------------------------------------------------------
template <bool OUT_BF16>
__global__ void agg128_kernel(const float* __restrict__ P,
                              const int* __restrict__ src,
                              const int* __restrict__ node_ptr,
                              const float* __restrict__ bias,
                              void* __restrict__ out) {
    const int wave = threadIdx.x >> 6;          // 0..3
    const int lane = threadIdx.x & 63;
    const int v    = blockIdx.x * 4 + wave;
    if (v >= N_NODES) return;

    const int lo = node_ptr[v];
    const int hi = node_ptr[v + 1];
    const float inv = 1.0f / (float)max(hi - lo, 1);

    const int half = lane >> 5;                 // 0 or 1
    const int c4   = lane & 31;                 // float4 slot

    float4 acc = make_float4(0.f, 0.f, 0.f, 0.f);
    for (int e = lo + half; e < hi; e += 2) {
        const int u = src[e];
        const float4 r = *reinterpret_cast<const float4*>(P + (size_t)u * HID + c4 * 4);
        acc.x += r.x; acc.y += r.y; acc.z += r.z; acc.w += r.w;
    }
    acc.x += __shfl_xor(acc.x, 32);
    acc.y += __shfl_xor(acc.y, 32);
    acc.z += __shfl_xor(acc.z, 32);
    acc.w += __shfl_xor(acc.w, 32);

    if (half == 0) {
        const float4 b4 = *reinterpret_cast<const float4*>(bias + c4 * 4);
        float o0 = fmaxf(acc.x * inv + b4.x, 0.f);
        float o1 = fmaxf(acc.y * inv + b4.y, 0.f);
        float o2 = fmaxf(acc.z * inv + b4.z, 0.f);
        float o3 = fmaxf(acc.w * inv + b4.w, 0.f);
        if (OUT_BF16) {
            ushort4 o;
            o.x = f2bf(o0); o.y = f2bf(o1); o.z = f2bf(o2); o.w = f2bf(o3);
            *reinterpret_cast<ushort4*>((unsigned short*)out + (size_t)v * HID + c4 * 4) = o;
        } else {
            float4 o = make_float4(o0, o1, o2, o3);
            *reinterpret_cast<float4*>((float*)out + (size_t)v * HID + c4 * 4) = o;
        }
    }
}

// ---------------------------------------------------------------------------
// Per-graph mean pooling (graph_id sorted). 8 partial blocks per graph.
// ---------------------------------------------------------------------------
__global__ void pool_kernel(const float* __restrict__ h,
                            const int* __restrict__ graph_ptr,
                            float* __restrict__ hg) {
    constexpr int SPLIT = 8;
    const int g   = blockIdx.x / SPLIT;
    const int s   = blockIdx.x % SPLIT;
    const int tid = threadIdx.x;                // 128
    const int lo  = graph_ptr[g];
    const int hi  = graph_ptr[g + 1];
    const float inv = 1.0f / (float)max(hi - lo, 1);

    float acc = 0.0f;
    for (int r = lo + s; r < hi; r += SPLIT)
        acc += h[(size_t)r * HID + tid];
    if (acc != 0.0f || s == 0)
        atomicAdd(&hg[g * HID + tid], acc * inv);
}

// ---------------------------------------------------------------------------
// Classifier head (fp32, tiny).
// ---------------------------------------------------------------------------
__global__ void cls1_kernel(const float* __restrict__ hg,
                            const float* __restrict__ Wc1,
                            const float* __restrict__ bc1,
                            float* __restrict__ t) {
    const int g = blockIdx.x;                   // 64
    const int j = threadIdx.x;                  // 128
    __shared__ float row[HID];
    row[j] = hg[g * HID + j];
    __syncthreads();
    float acc = bc1[j];
    for (int k = 0; k < HID; ++k) acc += row[k] * Wc1[k * HID + j];
    t[g * HID + j] = fmaxf(acc, 0.0f);
}

__global__ void cls2_kernel(const float* __restrict__ t,
                            const float* __restrict__ Wc2,
                            const float* __restrict__ bc2,
                            float* __restrict__ out) {
    const int g = blockIdx.x;                   // 64
    const int j = threadIdx.x;                  // 64
    __shared__ float row[HID];
    row[j]      = t[g * HID + j];
    row[j + 64] = t[g * HID + j + 64];
    __syncthreads();
    float acc = bc2[j];
    for (int k = 0; k < HID; ++k) acc += row[k] * Wc2[k * N_CLASSES + j];
    out[g * N_CLASSES + j] = acc;
}

// ---------------------------------------------------------------------------
extern "C" void kernel_launch(void* const* d_in, const int* in_sizes, int n_in,
                              void* d_out, int out_size, void* d_ws, size_t ws_size,
                              hipStream_t stream) {
    const float* nf   = (const float*)d_in[0];
    const int*   src  = (const int*)  d_in[1];
    const int*   dst  = (const int*)  d_in[2];
    const int*   gid  = (const int*)  d_in[3];
    const float* W1  = (const float*)d_in[5];
    const float* b1  = (const float*)d_in[6];
    const float* W2  = (const float*)d_in[7];
    const float* b2  = (const float*)d_in[8];
    const float* W3  = (const float*)d_in[9];
    const float* b3  = (const float*)d_in[10];
    const float* Wc1 = (const float*)d_in[11];
    const float* bc1 = (const float*)d_in[12];
    const float* Wc2 = (const float*)d_in[13];
    const float* bc2 = (const float*)d_in[14];
    float* out = (float*)d_out;

    char* ws = (char*)d_ws;
    size_t off = 0;
    auto alloc = [&](size_t bytes) { void* p = ws + off; off = (off + bytes + 255) & ~(size_t)255; return p; };
    int*   node_ptr  = (int*)  alloc((N_NODES + 1) * sizeof(int));
    int*   graph_ptr = (int*)  alloc((N_GRAPHS + 1) * sizeof(int));
    // region A: nfb (bf16 M x 96, 9.6 MB) dead after GEMM1; h3 (fp32 M x 128) written later
    char*  regionA   = (char*) alloc((size_t)N_NODES * HID * sizeof(float));
    unsigned short* nfb = (unsigned short*)regionA;
    float*          h3  = (float*)regionA;
    float* P         = (float*)alloc((size_t)N_NODES * HID * sizeof(float));
    unsigned short* hb = (unsigned short*)alloc((size_t)N_NODES * HID * sizeof(unsigned short)); // h1b/h2b
    unsigned short* wt1 = (unsigned short*)alloc((size_t)HID * KP1 * sizeof(unsigned short));
    unsigned short* wt2 = (unsigned short*)alloc((size_t)HID * HID * sizeof(unsigned short));
    unsigned short* wt3 = (unsigned short*)alloc((size_t)HID * HID * sizeof(unsigned short));
    float* hg        = (float*)alloc(N_GRAPHS * HID * sizeof(float));
    float* tbuf      = (float*)alloc(N_GRAPHS * HID * sizeof(float));
    (void)ws_size;

    const int AGG_GRID  = (N_NODES + 3) / 4;
    const int GEMM_GRID = (N_NODES + 63) / 64;

    // prep: CSR pointers, input/weight conversion
    rowptr_kernel<<<(N_NODES + 256) / 256, 256, 0, stream>>>(dst, gid, node_ptr, graph_ptr);
    conv_nf_kernel<<<(N_NODES * KP1 + 255) / 256, 256, 0, stream>>>(nf, nfb);
    prep_wt_kernel<IN_DIM, KP1><<<(HID * KP1 + 255) / 256, 256, 0, stream>>>(W1, wt1);
    prep_wt_kernel<HID, HID><<<(HID * HID + 255) / 256, 256, 0, stream>>>(W2, wt2);
    prep_wt_kernel<HID, HID><<<(HID * HID + 255) / 256, 256, 0, stream>>>(W3, wt3);

    // Layer 1: P = nfb @ W1 ; h1b = bf16(relu(agg(P) + b1))
    mfma_gemm_kernel<KP1><<<GEMM_GRID, 256, 0, stream>>>(nfb, wt1, P, N_NODES);
    agg128_kernel<true><<<AGG_GRID, 256, 0, stream>>>(P, src, node_ptr, b1, hb);

    // Layer 2: P = h1b @ W2 ; h2b = bf16(relu(agg(P) + b2))  (hb reused in place)
    mfma_gemm_kernel<HID><<<GEMM_GRID, 256, 0, stream>>>(hb, wt2, P, N_NODES);
    agg128_kernel<true><<<AGG_GRID, 256, 0, stream>>>(P, src, node_ptr, b2, hb);

    // Layer 3: P = h2b @ W3 ; h3 = fp32(relu(agg(P) + b3))
    mfma_gemm_kernel<HID><<<GEMM_GRID, 256, 0, stream>>>(hb, wt3, P, N_NODES);
    agg128_kernel<false><<<AGG_GRID, 256, 0, stream>>>(P, src, node_ptr, b3, h3);

    // Graph mean pool
    hipMemsetAsync(hg, 0, N_GRAPHS * HID * sizeof(float), stream);
    pool_kernel<<<N_GRAPHS * 8, HID, 0, stream>>>(h3, graph_ptr, hg);

    // Classifier head
    cls1_kernel<<<N_GRAPHS, HID, 0, stream>>>(hg, Wc1, bc1, tbuf);
    cls2_kernel<<<N_GRAPHS, N_CLASSES, 0, stream>>>(tbuf, Wc2, bc2, out);
}

// Round 5
// 232.682 us; speedup vs baseline: 2.4015x; 1.2833x over previous
//
#include <hip/hip_runtime.h>

#define N_NODES   50000
#define N_EDGES   800000
#define IN_DIM    89
#define KP1       96      // IN_DIM padded to multiple of 32
#define HID       128
#define N_CLASSES 64
#define N_GRAPHS  64

typedef __attribute__((ext_vector_type(8))) short bf16x8;
typedef __attribute__((ext_vector_type(4))) float f32x4;

__device__ __forceinline__ unsigned short f2bf(float x) {
    union { float f; unsigned u; } v; v.f = x;
    unsigned r = v.u + 0x7FFF + ((v.u >> 16) & 1);   // RTNE
    return (unsigned short)(r >> 16);
}
__device__ __forceinline__ float bf2f(unsigned short x) {
    union { unsigned u; float f; } v; v.u = ((unsigned)x) << 16;
    return v.f;
}

// ---------------------------------------------------------------------------
// row_ptr via binary search: dst is sorted, graph_id is sorted.
// ---------------------------------------------------------------------------
__global__ void rowptr_kernel(const int* __restrict__ dst,
                              const int* __restrict__ gid,
                              int* __restrict__ node_ptr,
                              int* __restrict__ graph_ptr) {
    int i = blockIdx.x * blockDim.x + threadIdx.x;
    if (i <= N_NODES) {
        int lo = 0, hi = N_EDGES;
        while (lo < hi) { int mid = (lo + hi) >> 1; if (dst[mid] < i) lo = mid + 1; else hi = mid; }
        node_ptr[i] = lo;
    }
    if (i <= N_GRAPHS) {
        int lo = 0, hi = N_NODES;
        while (lo < hi) { int mid = (lo + hi) >> 1; if (gid[mid] < i) lo = mid + 1; else hi = mid; }
        graph_ptr[i] = lo;
    }
}

// ---------------------------------------------------------------------------
// nf (fp32, [M][89]) -> nfb (bf16, [M][96], zero-padded)
// ---------------------------------------------------------------------------
__global__ void conv_nf_kernel(const float* __restrict__ nf,
                               unsigned short* __restrict__ nfb) {
    const int i = blockIdx.x * 256 + threadIdx.x;
    if (i >= N_NODES * KP1) return;
    const int row = i / KP1, k = i - row * KP1;
    nfb[i] = (k < IN_DIM) ? f2bf(nf[(size_t)row * IN_DIM + k]) : (unsigned short)0;
}

// ---------------------------------------------------------------------------
// W (fp32, [K][128]) -> WT (bf16, [128][KPAD], transposed, zero-padded)
// ---------------------------------------------------------------------------
template <int K, int KPAD>
__global__ void prep_wt_kernel(const float* __restrict__ W,
                               unsigned short* __restrict__ WT) {
    const int i = blockIdx.x * 256 + threadIdx.x;
    if (i >= HID * KPAD) return;
    const int col = i / KPAD, k = i - col * KPAD;
    WT[i] = (k < K) ? f2bf(W[(size_t)k * HID + col]) : (unsigned short)0;
}

// ---------------------------------------------------------------------------
// MFMA GEMM: Y[M x 128](bf16) = Xb[M x KPAD](bf16) @ W (via WT[128 x KPAD]).
// Block = 256 threads = 4 waves; wave handles 16 rows x 128 cols. No LDS.
// D layout: row=(l>>4)*4+reg, col=(l&15)   [m89/m91-verified]
// ---------------------------------------------------------------------------
template <int KPAD>
__global__ __launch_bounds__(256) void mfma_gemm_kernel(
        const unsigned short* __restrict__ Xb,
        const unsigned short* __restrict__ WT,
        unsigned short* __restrict__ Y, int M) {
    const int wave = threadIdx.x >> 6;
    const int lane = threadIdx.x & 63;
    const int r    = lane & 15;
    const int kg   = lane >> 4;                 // 0..3

    const int row  = blockIdx.x * 64 + wave * 16 + r;
    const int rowc = (row < M) ? row : (M - 1); // clamp loads; stores masked

    f32x4 acc[8];
#pragma unroll
    for (int i = 0; i < 8; ++i) acc[i] = (f32x4){0.f, 0.f, 0.f, 0.f};

    const unsigned short* xrow = Xb + (size_t)rowc * KPAD + kg * 8;

#pragma unroll
    for (int k0 = 0; k0 < KPAD; k0 += 32) {
        const bf16x8 a = *reinterpret_cast<const bf16x8*>(xrow + k0);
#pragma unroll
        for (int nf = 0; nf < 8; ++nf) {
            const bf16x8 b = *reinterpret_cast<const bf16x8*>(
                WT + (size_t)(nf * 16 + r) * KPAD + kg * 8 + k0);
            acc[nf] = __builtin_amdgcn_mfma_f32_16x16x32_bf16(a, b, acc[nf], 0, 0, 0);
        }
    }

    const int orow0 = blockIdx.x * 64 + wave * 16 + kg * 4;
#pragma unroll
    for (int nf = 0; nf < 8; ++nf) {
#pragma unroll
        for (int q = 0; q < 4; ++q) {
            const int orow = orow0 + q;
            if (orow < M) Y[(size_t)orow * HID + nf * 16 + r] = f2bf(acc[nf][q]);
        }
    }
}

// ---------------------------------------------------------------------------
// 128-dim mean aggregation + bias + ReLU over bf16 P, wave-per-node.
// 16 lanes/edge x bf16x8 (16 B) -> 4 edges per wave instruction.
// Quarters combined with shfl_xor(16), shfl_xor(32). fp32 accumulate.
// OUT_BF16: write bf16 (feeds next GEMM); else fp32 (feeds pool).
// ---------------------------------------------------------------------------
template <bool OUT_BF16>
__global__ void agg128_kernel(const unsigned short* __restrict__ Pb,
                              const int* __restrict__ src,
                              const int* __restrict__ node_ptr,
                              const float* __restrict__ bias,
                              void* __restrict__ out) {
    const int wave = threadIdx.x >> 6;          // 0..3
    const int lane = threadIdx.x & 63;
    const int v    = blockIdx.x * 4 + wave;
    if (v >= N_NODES) return;

    const int lo = node_ptr[v];
    const int hi = node_ptr[v + 1];
    const float inv = 1.0f / (float)max(hi - lo, 1);

    const int q = lane >> 4;                    // edge sub-slot 0..3
    const int g = lane & 15;                    // dim group: dims [8g, 8g+8)

    float acc[8];
#pragma unroll
    for (int j = 0; j < 8; ++j) acc[j] = 0.f;

    for (int e = lo + q; e < hi; e += 4) {
        const int u = src[e];
        const bf16x8 r = *reinterpret_cast<const bf16x8*>(Pb + (size_t)u * HID + g * 8);
#pragma unroll
        for (int j = 0; j < 8; ++j) acc[j] += bf2f((unsigned short)r[j]);
    }
#pragma unroll
    for (int j = 0; j < 8; ++j) {
        acc[j] += __shfl_xor(acc[j], 16);
        acc[j] += __shfl_xor(acc[j], 32);
    }

    if (q == 0) {
        const float4 b0 = *reinterpret_cast<const float4*>(bias + g * 8);
        const float4 b1 = *reinterpret_cast<const float4*>(bias + g * 8 + 4);
        float o[8];
        o[0] = fmaxf(acc[0] * inv + b0.x, 0.f);
        o[1] = fmaxf(acc[1] * inv + b0.y, 0.f);
        o[2] = fmaxf(acc[2] * inv + b0.z, 0.f);
        o[3] = fmaxf(acc[3] * inv + b0.w, 0.f);
        o[4] = fmaxf(acc[4] * inv + b1.x, 0.f);
        o[5] = fmaxf(acc[5] * inv + b1.y, 0.f);
        o[6] = fmaxf(acc[6] * inv + b1.z, 0.f);
        o[7] = fmaxf(acc[7] * inv + b1.w, 0.f);
        if (OUT_BF16) {
            bf16x8 ob;
#pragma unroll
            for (int j = 0; j < 8; ++j) ob[j] = (short)f2bf(o[j]);
            *reinterpret_cast<bf16x8*>((unsigned short*)out + (size_t)v * HID + g * 8) = ob;
        } else {
            float4 a = make_float4(o[0], o[1], o[2], o[3]);
            float4 b = make_float4(o[4], o[5], o[6], o[7]);
            *reinterpret_cast<float4*>((float*)out + (size_t)v * HID + g * 8)     = a;
            *reinterpret_cast<float4*>((float*)out + (size_t)v * HID + g * 8 + 4) = b;
        }
    }
}

// ---------------------------------------------------------------------------
// Per-graph mean pooling (graph_id sorted). 8 partial blocks per graph.
// ---------------------------------------------------------------------------
__global__ void pool_kernel(const float* __restrict__ h,
                            const int* __restrict__ graph_ptr,
                            float* __restrict__ hg) {
    constexpr int SPLIT = 8;
    const int g   = blockIdx.x / SPLIT;
    const int s   = blockIdx.x % SPLIT;
    const int tid = threadIdx.x;                // 128
    const int lo  = graph_ptr[g];
    const int hi  = graph_ptr[g + 1];
    const float inv = 1.0f / (float)max(hi - lo, 1);

    float acc = 0.0f;
    for (int r = lo + s; r < hi; r += SPLIT)
        acc += h[(size_t)r * HID + tid];
    if (acc != 0.0f || s == 0)
        atomicAdd(&hg[g * HID + tid], acc * inv);
}

// ---------------------------------------------------------------------------
// Classifier head (fp32, tiny).
// ---------------------------------------------------------------------------
__global__ void cls1_kernel(const float* __restrict__ hg,
                            const float* __restrict__ Wc1,
                            const float* __restrict__ bc1,
                            float* __restrict__ t) {
    const int g = blockIdx.x;                   // 64
    const int j = threadIdx.x;                  // 128
    __shared__ float row[HID];
    row[j] = hg[g * HID + j];
    __syncthreads();
    float acc = bc1[j];
    for (int k = 0; k < HID; ++k) acc += row[k] * Wc1[k * HID + j];
    t[g * HID + j] = fmaxf(acc, 0.0f);
}

__global__ void cls2_kernel(const float* __restrict__ t,
                            const float* __restrict__ Wc2,
                            const float* __restrict__ bc2,
                            float* __restrict__ out) {
    const int g = blockIdx.x;                   // 64
    const int j = threadIdx.x;                  // 64
    __shared__ float row[HID];
    row[j]      = t[g * HID + j];
    row[j + 64] = t[g * HID + j + 64];
    __syncthreads();
    float acc = bc2[j];
    for (int k = 0; k < HID; ++k) acc += row[k] * Wc2[k * N_CLASSES + j];
    out[g * N_CLASSES + j] = acc;
}

// ---------------------------------------------------------------------------
extern "C" void kernel_launch(void* const* d_in, const int* in_sizes, int n_in,
                              void* d_out, int out_size, void* d_ws, size_t ws_size,
                              hipStream_t stream) {
    const float* nf   = (const float*)d_in[0];
    const int*   src  = (const int*)  d_in[1];
    const int*   dst  = (const int*)  d_in[2];
    const int*   gid  = (const int*)  d_in[3];
    const float* W1  = (const float*)d_in[5];
    const float* b1  = (const float*)d_in[6];
    const float* W2  = (const float*)d_in[7];
    const float* b2  = (const float*)d_in[8];
    const float* W3  = (const float*)d_in[9];
    const float* b3  = (const float*)d_in[10];
    const float* Wc1 = (const float*)d_in[11];
    const float* bc1 = (const float*)d_in[12];
    const float* Wc2 = (const float*)d_in[13];
    const float* bc2 = (const float*)d_in[14];
    float* out = (float*)d_out;

    char* ws = (char*)d_ws;
    size_t off = 0;
    auto alloc = [&](size_t bytes) { void* p = ws + off; off = (off + bytes + 255) & ~(size_t)255; return p; };
    int*   node_ptr  = (int*)  alloc((N_NODES + 1) * sizeof(int));
    int*   graph_ptr = (int*)  alloc((N_GRAPHS + 1) * sizeof(int));
    // region A: nfb (bf16 M x 96) dead after GEMM1; later reused for h3 (fp32 M x 128)
    char*  regionA   = (char*) alloc((size_t)N_NODES * HID * sizeof(float));
    unsigned short* nfb = (unsigned short*)regionA;
    float*          h3  = (float*)regionA;
    unsigned short* Pb  = (unsigned short*)alloc((size_t)N_NODES * HID * sizeof(unsigned short));
    unsigned short* hb  = (unsigned short*)alloc((size_t)N_NODES * HID * sizeof(unsigned short));
    unsigned short* wt1 = (unsigned short*)alloc((size_t)HID * KP1 * sizeof(unsigned short));
    unsigned short* wt2 = (unsigned short*)alloc((size_t)HID * HID * sizeof(unsigned short));
    unsigned short* wt3 = (unsigned short*)alloc((size_t)HID * HID * sizeof(unsigned short));
    float* hg        = (float*)alloc(N_GRAPHS * HID * sizeof(float));
    float* tbuf      = (float*)alloc(N_GRAPHS * HID * sizeof(float));
    (void)ws_size;

    const int AGG_GRID  = (N_NODES + 3) / 4;
    const int GEMM_GRID = (N_NODES + 63) / 64;

    // prep: CSR pointers, input/weight conversion
    rowptr_kernel<<<(N_NODES + 256) / 256, 256, 0, stream>>>(dst, gid, node_ptr, graph_ptr);
    conv_nf_kernel<<<(N_NODES * KP1 + 255) / 256, 256, 0, stream>>>(nf, nfb);
    prep_wt_kernel<IN_DIM, KP1><<<(HID * KP1 + 255) / 256, 256, 0, stream>>>(W1, wt1);
    prep_wt_kernel<HID, HID><<<(HID * HID + 255) / 256, 256, 0, stream>>>(W2, wt2);
    prep_wt_kernel<HID, HID><<<(HID * HID + 255) / 256, 256, 0, stream>>>(W3, wt3);

    // Layer 1: Pb = nfb @ W1 ; hb = bf16(relu(agg(Pb) + b1))
    mfma_gemm_kernel<KP1><<<GEMM_GRID, 256, 0, stream>>>(nfb, wt1, Pb, N_NODES);
    agg128_kernel<true><<<AGG_GRID, 256, 0, stream>>>(Pb, src, node_ptr, b1, hb);

    // Layer 2
    mfma_gemm_kernel<HID><<<GEMM_GRID, 256, 0, stream>>>(hb, wt2, Pb, N_NODES);
    agg128_kernel<true><<<AGG_GRID, 256, 0, stream>>>(Pb, src, node_ptr, b2, hb);

    // Layer 3: h3 fp32 for pooling
    mfma_gemm_kernel<HID><<<GEMM_GRID, 256, 0, stream>>>(hb, wt3, Pb, N_NODES);
    agg128_kernel<false><<<AGG_GRID, 256, 0, stream>>>(Pb, src, node_ptr, b3, h3);

    // Graph mean pool
    hipMemsetAsync(hg, 0, N_GRAPHS * HID * sizeof(float), stream);
    pool_kernel<<<N_GRAPHS * 8, HID, 0, stream>>>(h3, graph_ptr, hg);

    // Classifier head
    cls1_kernel<<<N_GRAPHS, HID, 0, stream>>>(hg, Wc1, bc1, tbuf);
    cls2_kernel<<<N_GRAPHS, N_CLASSES, 0, stream>>>(tbuf, Wc2, bc2, out);
}